// Round 8
// baseline (1986.527 us; speedup 1.0000x reference)
//
#include <hip/hip_runtime.h>
#include <hip/hip_bf16.h>
#include <cstdint>

// LSTM B=256 T=512 F=256 H=512 — persistent kernel, round 8.
// Round 7 failed: x-prefetch was untracked inline-asm loads whose non-volatile
// cvt consumers could be hoisted above any covering waitcnt (rule #18 class).
// Round 8 = round 7 structure, hazard surface removed:
//  - x prefetch: normal C++ float4 loads (compiler-tracked waits; round-5
//    proven), issued BEFORE the poll so they retire in the wait window.
//  - h loads: direct-to-register asm, SELF-CONTAINED (ends s_waitcnt vmcnt(0))
//    + sched_barrier(0) before the consuming MFMAs. No counted vmcnt.
//  - kept: 4-way K-split (wave wk: x[wk*64,+64) + h[wk*128,+128), all 4
//    gates; zero h-read duplication), h->A-fragment direct (no LDS for h),
//    split-K reduce via Gsh, out[t-1] off the publish chain, parity hbuf +
//    sc0 sc1 flag fabric (round-5 proven protocol, unchanged).
// ws: BT 3MB @0 | hbuf[2] 512KB @0x300000 | flags 16KB @0x380000.

#define B_   256
#define T_   512
#define F_   256
#define H_   512
#define K_   768
#define NG_  2048
#define AWX  264   // Ash bf16 row stride: 256 + 8 pad

typedef __attribute__((ext_vector_type(8))) short short8;
typedef __attribute__((ext_vector_type(4))) float f32x4;

static __device__ __forceinline__ unsigned short f2bf(float f) {
  union { float f; unsigned u; } v; v.f = f;
  unsigned r = v.u + 0x7FFFu + ((v.u >> 16) & 1u);   // RNE
  return (unsigned short)(r >> 16);
}
static __device__ __forceinline__ float sigmoid_f(float x) {
  return __builtin_amdgcn_rcpf(1.f + __expf(-x));
}
static __device__ __forceinline__ float tanh_f(float x) {
  return 1.f - 2.f * __builtin_amdgcn_rcpf(__expf(2.f * x) + 1.f);
}
#define BAR_LDS() asm volatile("s_waitcnt lgkmcnt(0)\n\ts_barrier" ::: "memory")

__global__ void prep_weights(const float* __restrict__ Wi, const float* __restrict__ Wf,
                             const float* __restrict__ Wo, const float* __restrict__ Wc,
                             const float* __restrict__ Ui, const float* __restrict__ Uf,
                             const float* __restrict__ Uo, const float* __restrict__ Uc,
                             unsigned short* __restrict__ BT,
                             unsigned* __restrict__ flags) {
  if (blockIdx.x == 0) {                      // re-zero step flags every call
    unsigned* fp = flags + threadIdx.x * 16;
    unsigned z = 0;
    asm volatile("global_store_dword %0, %1, off sc0 sc1" :: "v"(fp), "v"(z) : "memory");
  }
  int idx = blockIdx.x * 256 + threadIdx.x;
  if (idx >= NG_ * K_) return;
  int col = idx / K_;
  int k   = idx - col * K_;
  int gate = col >> 9;       // 0:i 1:f 2:o 3:c (reference concat order)
  int hc   = col & 511;
  const float* Wg = (gate == 0) ? Wi : (gate == 1) ? Wf : (gate == 2) ? Wo : Wc;
  const float* Ug = (gate == 0) ? Ui : (gate == 1) ? Uf : (gate == 2) ? Uo : Uc;
  float v = (k < F_) ? Wg[k * H_ + hc] : Ug[(k - F_) * H_ + hc];
  BT[idx] = f2bf(v);
}

// D = A*B + D for all 4 gates, one K-chunk. FA: rows l15, FB: rows 16+l15.
#define MFMA4(FA, FB, KK)                                                       \
  g0a = __builtin_amdgcn_mfma_f32_16x16x32_bf16(FA, Brg[0][KK], g0a, 0, 0, 0);  \
  g0b = __builtin_amdgcn_mfma_f32_16x16x32_bf16(FB, Brg[0][KK], g0b, 0, 0, 0);  \
  g1a = __builtin_amdgcn_mfma_f32_16x16x32_bf16(FA, Brg[1][KK], g1a, 0, 0, 0);  \
  g1b = __builtin_amdgcn_mfma_f32_16x16x32_bf16(FB, Brg[1][KK], g1b, 0, 0, 0);  \
  g2a = __builtin_amdgcn_mfma_f32_16x16x32_bf16(FA, Brg[2][KK], g2a, 0, 0, 0);  \
  g2b = __builtin_amdgcn_mfma_f32_16x16x32_bf16(FB, Brg[2][KK], g2b, 0, 0, 0);  \
  g3a = __builtin_amdgcn_mfma_f32_16x16x32_bf16(FA, Brg[3][KK], g3a, 0, 0, 0);  \
  g3b = __builtin_amdgcn_mfma_f32_16x16x32_bf16(FB, Brg[3][KK], g3b, 0, 0, 0)

__global__ __launch_bounds__(256, 1)
void lstm_persist(const float* __restrict__ x,
                  const unsigned short* __restrict__ BT,
                  const float* __restrict__ bi, const float* __restrict__ bfp,
                  const float* __restrict__ bo, const float* __restrict__ bc,
                  float* __restrict__ out,
                  unsigned* __restrict__ flags,
                  unsigned short* __restrict__ hbuf) {
  __shared__ __align__(16) unsigned short Ash[32][AWX];   // x_t tile (bf16)
  __shared__ float Gsh[4][4][32][18];                     // [wk][gate][row][col]

  const int tid = threadIdx.x;
  const int rg = blockIdx.x & 7;     // group (32 batch rows)
  const int cg = blockIdx.x >> 3;    // 16 h-cols strip (= flag slot)
  const int wave = tid >> 6, lane = tid & 63;
  const int wk = wave;               // K-slice: x[wk*64,+64) + h[wk*128,+128)
  const int l15 = lane & 15, l4 = lane >> 4;

  // ---- persistent weights: 4 gates x 6 K-chunks = 96 VGPRs ----
  short8 Brg[4][6];
  #pragma unroll
  for (int g = 0; g < 4; ++g) {
    const unsigned short* Bp = BT + (size_t)((g << 9) | (cg << 4) | l15) * K_;
    #pragma unroll
    for (int kk = 0; kk < 6; ++kk) {
      const int k = (kk < 2) ? (wk * 64 + kk * 32) : (256 + wk * 128 + (kk - 2) * 32);
      Brg[g][kk] = *reinterpret_cast<const short8*>(Bp + k + l4 * 8);
    }
  }

  // ---- gate-math mapping: 2 outputs (row grow_r, cols hcg..hcg+1) ----
  const int grow_r = tid >> 3;
  const int gcol0 = (tid & 7) * 2;
  const int hcg = (cg << 4) + gcol0;
  const float bi0 = bi[hcg],  bi1 = bi[hcg + 1];
  const float bf0 = bfp[hcg], bf1 = bfp[hcg + 1];
  const float bo0 = bo[hcg],  bo1 = bo[hcg + 1];
  const float bc0 = bc[hcg],  bc1 = bc[hcg + 1];
  float cc0 = 0.f, cc1 = 0.f;
  float h0v = 0.f, h1v = 0.f;
  const int grow = rg * 32 + grow_r;
  float* outp = out + (size_t)grow * T_ * H_ + hcg;
  unsigned* hbp0 = reinterpret_cast<unsigned*>(hbuf + (size_t)grow * H_ + hcg);
  unsigned* hbp1 = reinterpret_cast<unsigned*>(hbuf + (size_t)(B_ + grow) * H_ + hcg);

  // ---- address prep ----
  // h A-fragment voffsets: row l15 (voA) / row 16+l15 (voB), col wk*128+l4*8
  const unsigned voA = (unsigned)(((rg * 32 + l15) * H_ + wk * 128 + l4 * 8) * 2);
  const unsigned voB = voA + (unsigned)(16 * H_ * 2);
  const unsigned short* hsrc0 = hbuf;
  const unsigned short* hsrc1 = hbuf + (size_t)B_ * H_;
  unsigned* myflag = flags + (rg * 32 + cg) * 16;
  // wave wk needs h-col strips wk*8..wk*8+7 -> lane polls peer wk*8+(lane&7)
  const unsigned* pollp = flags + (rg * 32 + wk * 8 + (lane & 7)) * 16;

  // ---- stage x(0) into Ash (bf16) ----
  #pragma unroll
  for (int j = 0; j < 8; ++j) {
    int f = tid + 256 * j; int row = f >> 6, k4 = f & 63;
    const float4 v = *reinterpret_cast<const float4*>(
        x + (size_t)(rg * 32 + row) * T_ * F_ + k4 * 4);
    unsigned lo, hi;
    asm("v_cvt_pk_bf16_f32 %0, %1, %2" : "=v"(lo) : "v"(v.x), "v"(v.y));
    asm("v_cvt_pk_bf16_f32 %0, %1, %2" : "=v"(hi) : "v"(v.z), "v"(v.w));
    uint2 p; p.x = lo; p.y = hi;
    *reinterpret_cast<uint2*>(&Ash[row][k4 * 4]) = p;
  }
  __syncthreads();

  for (int t = 0; t < T_; ++t) {
    f32x4 g0a = {0,0,0,0}, g0b = {0,0,0,0}, g1a = {0,0,0,0}, g1b = {0,0,0,0};
    f32x4 g2a = {0,0,0,0}, g2b = {0,0,0,0}, g3a = {0,0,0,0}, g3b = {0,0,0,0};

    // ---- A) x-part MFMA (kk 0..1): no h dependence, hides peer wait ----
    {
      const short8 xa0 = *reinterpret_cast<const short8*>(&Ash[l15][wk * 64 + l4 * 8]);
      const short8 xb0 = *reinterpret_cast<const short8*>(&Ash[16 + l15][wk * 64 + l4 * 8]);
      MFMA4(xa0, xb0, 0);
      const short8 xa1 = *reinterpret_cast<const short8*>(&Ash[l15][wk * 64 + 32 + l4 * 8]);
      const short8 xb1 = *reinterpret_cast<const short8*>(&Ash[16 + l15][wk * 64 + 32 + l4 * 8]);
      MFMA4(xa1, xb1, 1);
    }

    // ---- A2) x(t+1) prefetch: NORMAL loads (compiler-tracked waits);
    //      issued before the poll so they retire during the wait window ----
    float4 xv[8];
    if (t + 1 < T_) {
      #pragma unroll
      for (int j = 0; j < 8; ++j) {
        xv[j] = *reinterpret_cast<const float4*>(
            x + ((size_t)(rg * 32 + wave + 4 * j) * T_ + (t + 1)) * F_ + lane * 4);
      }
    }

    // ---- B) poll the 8 producer blocks of this wave's h-col strips ----
    short8 hA0, hA1, hA2, hA3, hB0, hB1, hB2, hB3;
    if (t > 0) {
      const unsigned want = (unsigned)t;
      unsigned cur;
      do {
        asm volatile("global_load_dword %0, %1, off sc0 sc1\n\ts_waitcnt vmcnt(0)"
                     : "=v"(cur) : "v"(pollp) : "memory");
      } while (cur < want);
      // ---- C) h A-fragments direct to registers, SELF-DRAINING asm ----
      const unsigned short* hsrc = ((t - 1) & 1) ? hsrc1 : hsrc0;
      asm volatile(
        "global_load_dwordx4 %0, %8, %10 sc0 sc1\n\t"
        "global_load_dwordx4 %1, %8, %10 offset:64 sc0 sc1\n\t"
        "global_load_dwordx4 %2, %8, %10 offset:128 sc0 sc1\n\t"
        "global_load_dwordx4 %3, %8, %10 offset:192 sc0 sc1\n\t"
        "global_load_dwordx4 %4, %9, %10 sc0 sc1\n\t"
        "global_load_dwordx4 %5, %9, %10 offset:64 sc0 sc1\n\t"
        "global_load_dwordx4 %6, %9, %10 offset:128 sc0 sc1\n\t"
        "global_load_dwordx4 %7, %9, %10 offset:192 sc0 sc1\n\t"
        "s_waitcnt vmcnt(0)"
        : "=&v"(hA0), "=&v"(hA1), "=&v"(hA2), "=&v"(hA3),
          "=&v"(hB0), "=&v"(hB1), "=&v"(hB2), "=&v"(hB3)
        : "v"(voA), "v"(voB), "s"(hsrc)
        : "memory");
      __builtin_amdgcn_sched_barrier(0);                 // rule #18 fence

      // ---- D) h-part MFMA (kk 2..5) ----
      MFMA4(hA0, hB0, 2);
      MFMA4(hA1, hB1, 3);
      MFMA4(hA2, hB2, 4);
      MFMA4(hA3, hB3, 5);
      // out[t-1] store: off the publish chain (acked by F's drain)
      float2 hw; hw.x = h0v; hw.y = h1v;
      *reinterpret_cast<float2*>(outp + (size_t)(t - 1) * H_) = hw;
    }

    // ---- E) split-K partials to Gsh ----
    #pragma unroll
    for (int r = 0; r < 4; ++r) {                        // D: col=l15, row=l4*4+r
      Gsh[wk][0][l4 * 4 + r][l15] = g0a[r]; Gsh[wk][0][16 + l4 * 4 + r][l15] = g0b[r];
      Gsh[wk][1][l4 * 4 + r][l15] = g1a[r]; Gsh[wk][1][16 + l4 * 4 + r][l15] = g1b[r];
      Gsh[wk][2][l4 * 4 + r][l15] = g2a[r]; Gsh[wk][2][16 + l4 * 4 + r][l15] = g2b[r];
      Gsh[wk][3][l4 * 4 + r][l15] = g3a[r]; Gsh[wk][3][16 + l4 * 4 + r][l15] = g3b[r];
    }
    BAR_LDS();                                           // B2

    // ---- F) gates + cell update; publish h ----
    {
      float gi0 = bi0, gi1 = bi1, gf0 = bf0, gf1 = bf1;
      float go0 = bo0, go1 = bo1, gc0 = bc0, gc1 = bc1;
      #pragma unroll
      for (int w = 0; w < 4; ++w) {
        const float2 a = *reinterpret_cast<const float2*>(&Gsh[w][0][grow_r][gcol0]);
        const float2 b = *reinterpret_cast<const float2*>(&Gsh[w][1][grow_r][gcol0]);
        const float2 c = *reinterpret_cast<const float2*>(&Gsh[w][2][grow_r][gcol0]);
        const float2 d = *reinterpret_cast<const float2*>(&Gsh[w][3][grow_r][gcol0]);
        gi0 += a.x; gi1 += a.y; gf0 += b.x; gf1 += b.y;
        go0 += c.x; go1 += c.y; gc0 += d.x; gc1 += d.y;
      }
      const float it0 = sigmoid_f(gi0), it1 = sigmoid_f(gi1);
      const float ft0 = sigmoid_f(gf0), ft1 = sigmoid_f(gf1);
      const float ot0 = sigmoid_f(go0), ot1 = sigmoid_f(go1);
      const float ct0 = tanh_f(gc0),    ct1 = tanh_f(gc1);
      cc0 = ft0 * cc0 + it0 * ct0;
      cc1 = ft1 * cc1 + it1 * ct1;
      h0v = ot0 * tanh_f(cc0);
      h1v = ot1 * tanh_f(cc1);
      unsigned hp;
      asm("v_cvt_pk_bf16_f32 %0, %1, %2" : "=v"(hp) : "v"(h0v), "v"(h1v));
      unsigned* hq = (t & 1) ? hbp1 : hbp0;              // parity t&1 buffer
      asm volatile("global_store_dword %0, %1, off sc0 sc1"
                   :: "v"(hq), "v"(hp) : "memory");
    }
    asm volatile("s_waitcnt vmcnt(0)" ::: "memory");     // h store acked at IF$
    BAR_LDS();                                           // B3: whole block done
    if (tid == 0) {                                      // publish "step t done"
      unsigned val = (unsigned)(t + 1);
      asm volatile("global_store_dword %0, %1, off sc0 sc1"
                   :: "v"(myflag), "v"(val) : "memory");
    }

    // ---- G) off-chain: x(t+1) -> Ash (overlaps flag propagation) ----
    if (t + 1 < T_) {
      #pragma unroll
      for (int j = 0; j < 8; ++j) {
        unsigned lo, hi;
        asm("v_cvt_pk_bf16_f32 %0, %1, %2" : "=v"(lo) : "v"(xv[j].x), "v"(xv[j].y));
        asm("v_cvt_pk_bf16_f32 %0, %1, %2" : "=v"(hi) : "v"(xv[j].z), "v"(xv[j].w));
        uint2 p; p.x = lo; p.y = hi;
        *reinterpret_cast<uint2*>(&Ash[wave + 4 * j][lane * 4]) = p;
      }
    }
    BAR_LDS();                                           // loop-end: Ash ready
  }

  // final output row
  float2 hw; hw.x = h0v; hw.y = h1v;
  *reinterpret_cast<float2*>(outp + (size_t)(T_ - 1) * H_) = hw;
}

extern "C" void kernel_launch(void* const* d_in, const int* in_sizes, int n_in,
                              void* d_out, int out_size, void* d_ws, size_t ws_size,
                              hipStream_t stream) {
  const float* x  = (const float*)d_in[0];
  const float* Wi = (const float*)d_in[1];
  const float* Ui = (const float*)d_in[2];
  const float* bi = (const float*)d_in[3];
  const float* Wf = (const float*)d_in[4];
  const float* Uf = (const float*)d_in[5];
  const float* bf = (const float*)d_in[6];
  const float* Wc = (const float*)d_in[7];
  const float* Uc = (const float*)d_in[8];
  const float* bc = (const float*)d_in[9];
  const float* Wo = (const float*)d_in[10];
  const float* Uo = (const float*)d_in[11];
  const float* bo = (const float*)d_in[12];
  float* out = (float*)d_out;

  unsigned short* BT = (unsigned short*)d_ws;                          // 3 MB
  unsigned short* hbuf = (unsigned short*)((char*)d_ws + 0x300000);    // 512 KB
  unsigned* flags = (unsigned*)((char*)d_ws + 0x380000);               // 16 KB

  prep_weights<<<(NG_ * K_ + 255) / 256, 256, 0, stream>>>(
      Wi, Wf, Wo, Wc, Ui, Uf, Uo, Uc, BT, flags);

  void* args[] = {(void*)&x, (void*)&BT, (void*)&bi, (void*)&bf, (void*)&bo,
                  (void*)&bc, (void*)&out, (void*)&flags, (void*)&hbuf};
  hipLaunchCooperativeKernel(reinterpret_cast<const void*>(&lstm_persist),
                             dim3(256), dim3(256), args, 0, stream);
}

// Round 11
// 1975.331 us; speedup vs baseline: 1.0057x; 1.0057x over previous
//
#include <hip/hip_runtime.h>
#include <hip/hip_bf16.h>
#include <cstdint>

// LSTM B=256 T=512 F=256 H=512 — persistent kernel, round 11.
// Failure theory r9/r10: static LDS > 64KiB -> cooperative launch fails
// silently -> d_out all zeros. (r9 70656B, r10 86656B; all passing rounds
// <64K.) r10 also had AW=778 -> rows not 16B-aligned for ds_read_b128.
// Round 11 = round 8's PROVEN skeleton (LDS 53760B: x-only Ash 16.9K +
// Gsh[4][4][32][18] 36.9K; 4-way K-split; reg-direct h loads) with round
// 8's three chain mistakes fixed:
//  (1) x-MFMA runs INSIDE the h-load RTT: issue-asm (no wait) / C++
//      ds_read+MFMA / drain-asm vmcnt(0)+sched_barrier(0)  [rule-18].
//  (2) out[t] store after flag publish (off the publish chain).
//  (3) 3 barriers/step (B2, pre-publish, loop-end), lgkm-only except the
//      protocol-required vmcnt(0) h-store ack.
// Sync fabric unchanged from r5/r8 (proven): sc0 sc1 IF$ bypass, parity
// hbuf, per-block monotone flags, per-lane fused poll.
// ws: BT 3MB @0 | hbuf[2] 512KB @0x300000 | flags 16KB @0x380000.

#define B_   256
#define T_   512
#define F_   256
#define H_   512
#define K_   768
#define NG_  2048
#define AWX  264   // Ash bf16 row stride: 256 + 8 pad (528B, 16B-aligned)

typedef __attribute__((ext_vector_type(8))) short short8;
typedef __attribute__((ext_vector_type(4))) float f32x4;

static __device__ __forceinline__ unsigned short f2bf(float f) {
  union { float f; unsigned u; } v; v.f = f;
  unsigned r = v.u + 0x7FFFu + ((v.u >> 16) & 1u);   // RNE
  return (unsigned short)(r >> 16);
}
static __device__ __forceinline__ float sigmoid_f(float x) {
  return __builtin_amdgcn_rcpf(1.f + __expf(-x));
}
static __device__ __forceinline__ float tanh_f(float x) {
  return 1.f - 2.f * __builtin_amdgcn_rcpf(__expf(2.f * x) + 1.f);
}
#define BAR_LDS() asm volatile("s_waitcnt lgkmcnt(0)\n\ts_barrier" ::: "memory")

__global__ void prep_weights(const float* __restrict__ Wi, const float* __restrict__ Wf,
                             const float* __restrict__ Wo, const float* __restrict__ Wc,
                             const float* __restrict__ Ui, const float* __restrict__ Uf,
                             const float* __restrict__ Uo, const float* __restrict__ Uc,
                             unsigned short* __restrict__ BT,
                             unsigned* __restrict__ flags) {
  if (blockIdx.x == 0) {                      // re-zero step flags every call
    unsigned* fp = flags + threadIdx.x * 16;
    unsigned z = 0;
    asm volatile("global_store_dword %0, %1, off sc0 sc1" :: "v"(fp), "v"(z) : "memory");
  }
  int idx = blockIdx.x * 256 + threadIdx.x;
  if (idx >= NG_ * K_) return;
  int col = idx / K_;
  int k   = idx - col * K_;
  int gate = col >> 9;       // 0:i 1:f 2:o 3:c (reference concat order)
  int hc   = col & 511;
  const float* Wg = (gate == 0) ? Wi : (gate == 1) ? Wf : (gate == 2) ? Wo : Wc;
  const float* Ug = (gate == 0) ? Ui : (gate == 1) ? Uf : (gate == 2) ? Uo : Uc;
  float v = (k < F_) ? Wg[k * H_ + hc] : Ug[(k - F_) * H_ + hc];
  BT[idx] = f2bf(v);
}

// D = A*B + D for all 4 gates, one K-chunk. FA: rows l15, FB: rows 16+l15.
#define MFMA4(FA, FB, KK)                                                       \
  g0a = __builtin_amdgcn_mfma_f32_16x16x32_bf16(FA, Brg[0][KK], g0a, 0, 0, 0);  \
  g0b = __builtin_amdgcn_mfma_f32_16x16x32_bf16(FB, Brg[0][KK], g0b, 0, 0, 0);  \
  g1a = __builtin_amdgcn_mfma_f32_16x16x32_bf16(FA, Brg[1][KK], g1a, 0, 0, 0);  \
  g1b = __builtin_amdgcn_mfma_f32_16x16x32_bf16(FB, Brg[1][KK], g1b, 0, 0, 0);  \
  g2a = __builtin_amdgcn_mfma_f32_16x16x32_bf16(FA, Brg[2][KK], g2a, 0, 0, 0);  \
  g2b = __builtin_amdgcn_mfma_f32_16x16x32_bf16(FB, Brg[2][KK], g2b, 0, 0, 0);  \
  g3a = __builtin_amdgcn_mfma_f32_16x16x32_bf16(FA, Brg[3][KK], g3a, 0, 0, 0);  \
  g3b = __builtin_amdgcn_mfma_f32_16x16x32_bf16(FB, Brg[3][KK], g3b, 0, 0, 0)

__global__ __launch_bounds__(256, 1)
void lstm_persist(const float* __restrict__ x,
                  const unsigned short* __restrict__ BT,
                  const float* __restrict__ bi, const float* __restrict__ bfp,
                  const float* __restrict__ bo, const float* __restrict__ bc,
                  float* __restrict__ out,
                  unsigned* __restrict__ flags,
                  unsigned short* __restrict__ hbuf) {
  __shared__ __align__(16) unsigned short Ash[32][AWX];   // x_t tile (bf16)
  __shared__ float Gsh[4][4][32][18];                     // [wk][gate][row][col]
  // LDS total: 16896 + 36864 = 53760 B < 64 KiB  (r8-verified)

  const int tid = threadIdx.x;
  const int rg = blockIdx.x & 7;     // group (32 batch rows)
  const int cg = blockIdx.x >> 3;    // 16 h-cols strip (= flag slot)
  const int wave = tid >> 6, lane = tid & 63;
  const int wk = wave;               // K-slice: x[wk*64,+64) + h[wk*128,+128)
  const int l15 = lane & 15, l4 = lane >> 4;

  // ---- persistent weights: 4 gates x 6 K-chunks = 96 VGPRs ----
  short8 Brg[4][6];
  #pragma unroll
  for (int g = 0; g < 4; ++g) {
    const unsigned short* Bp = BT + (size_t)((g << 9) | (cg << 4) | l15) * K_;
    #pragma unroll
    for (int kk = 0; kk < 6; ++kk) {
      const int k = (kk < 2) ? (wk * 64 + kk * 32) : (256 + wk * 128 + (kk - 2) * 32);
      Brg[g][kk] = *reinterpret_cast<const short8*>(Bp + k + l4 * 8);
    }
  }

  // ---- gate-math mapping: 2 outputs (row grow_r, cols hcg..hcg+1) ----
  const int grow_r = tid >> 3;
  const int gcol0 = (tid & 7) * 2;
  const int hcg = (cg << 4) + gcol0;
  const float bi0 = bi[hcg],  bi1 = bi[hcg + 1];
  const float bf0 = bfp[hcg], bf1 = bfp[hcg + 1];
  const float bo0 = bo[hcg],  bo1 = bo[hcg + 1];
  const float bc0 = bc[hcg],  bc1 = bc[hcg + 1];
  float cc0 = 0.f, cc1 = 0.f;
  const int grow = rg * 32 + grow_r;
  float* outp = out + (size_t)grow * T_ * H_ + hcg;
  unsigned* hbp0 = reinterpret_cast<unsigned*>(hbuf + (size_t)grow * H_ + hcg);
  unsigned* hbp1 = reinterpret_cast<unsigned*>(hbuf + (size_t)(B_ + grow) * H_ + hcg);

  // ---- address prep ----
  // h A-fragment voffsets: row l15 (voA) / row l15+16 (voB), col wk*128+l4*8
  const unsigned voA = (unsigned)(((rg * 32 + l15) * H_ + wk * 128 + l4 * 8) * 2);
  const unsigned voB = voA + (unsigned)(16 * H_ * 2);
  const unsigned short* hsrc0 = hbuf;
  const unsigned short* hsrc1 = hbuf + (size_t)B_ * H_;
  unsigned* myflag = flags + (rg * 32 + cg) * 16;
  // wave wk needs h-col strips wk*8..wk*8+7 -> lane polls peer wk*8+(lane&7);
  // wave-level loop exit (all lanes pass) covers all 8 strips.
  const unsigned* pollp = flags + (rg * 32 + wk * 8 + (lane & 7)) * 16;

  // ---- stage x(0) into Ash (bf16) ----
  #pragma unroll
  for (int j = 0; j < 8; ++j) {
    int f = tid + 256 * j; int row = f >> 6, k4 = f & 63;
    const float4 v = *reinterpret_cast<const float4*>(
        x + (size_t)(rg * 32 + row) * T_ * F_ + k4 * 4);
    unsigned lo, hi;
    asm("v_cvt_pk_bf16_f32 %0, %1, %2" : "=v"(lo) : "v"(v.x), "v"(v.y));
    asm("v_cvt_pk_bf16_f32 %0, %1, %2" : "=v"(hi) : "v"(v.z), "v"(v.w));
    uint2 p; p.x = lo; p.y = hi;
    *reinterpret_cast<uint2*>(&Ash[row][k4 * 4]) = p;
  }
  __syncthreads();

  for (int t = 0; t < T_; ++t) {
    // ---- A) x(t+1) prefetch: normal loads, retire during the poll wait ----
    float4 xv[8];
    if (t + 1 < T_) {
      #pragma unroll
      for (int j = 0; j < 8; ++j) {
        xv[j] = *reinterpret_cast<const float4*>(
            x + ((size_t)(rg * 32 + wave + 4 * j) * T_ + (t + 1)) * F_ + lane * 4);
      }
    }

    f32x4 g0a = {0,0,0,0}, g0b = {0,0,0,0}, g1a = {0,0,0,0}, g1b = {0,0,0,0};
    f32x4 g2a = {0,0,0,0}, g2b = {0,0,0,0}, g3a = {0,0,0,0}, g3b = {0,0,0,0};

    if (t > 0) {
      // ---- B) poll the 8 producer blocks of this wave's h-col strips ----
      const unsigned want = (unsigned)t;
      unsigned cur;
      do {
        asm volatile("global_load_dword %0, %1, off sc0 sc1\n\ts_waitcnt vmcnt(0)"
                     : "=v"(cur) : "v"(pollp) : "memory");
      } while (cur < want);

      // ---- C) h A-fragments: ISSUE ONLY (no wait) ----
      const unsigned short* hsrc = ((t - 1) & 1) ? hsrc1 : hsrc0;
      short8 hA0, hA1, hA2, hA3, hB0, hB1, hB2, hB3;
      asm volatile(
        "global_load_dwordx4 %0, %8, %10 sc0 sc1\n\t"
        "global_load_dwordx4 %1, %8, %10 offset:64 sc0 sc1\n\t"
        "global_load_dwordx4 %2, %8, %10 offset:128 sc0 sc1\n\t"
        "global_load_dwordx4 %3, %8, %10 offset:192 sc0 sc1\n\t"
        "global_load_dwordx4 %4, %9, %10 sc0 sc1\n\t"
        "global_load_dwordx4 %5, %9, %10 offset:64 sc0 sc1\n\t"
        "global_load_dwordx4 %6, %9, %10 offset:128 sc0 sc1\n\t"
        "global_load_dwordx4 %7, %9, %10 offset:192 sc0 sc1"
        : "=&v"(hA0), "=&v"(hA1), "=&v"(hA2), "=&v"(hA3),
          "=&v"(hB0), "=&v"(hB1), "=&v"(hB2), "=&v"(hB3)
        : "v"(voA), "v"(voB), "s"(hsrc)
        : "memory");

      // ---- D) x-part MFMA (kk 0..1) hides inside the h-load RTT ----
      {
        const short8 xa0 = *reinterpret_cast<const short8*>(&Ash[l15][wk * 64 + l4 * 8]);
        const short8 xb0 = *reinterpret_cast<const short8*>(&Ash[16 + l15][wk * 64 + l4 * 8]);
        MFMA4(xa0, xb0, 0);
        const short8 xa1 = *reinterpret_cast<const short8*>(&Ash[l15][wk * 64 + 32 + l4 * 8]);
        const short8 xb1 = *reinterpret_cast<const short8*>(&Ash[16 + l15][wk * 64 + 32 + l4 * 8]);
        MFMA4(xa1, xb1, 1);
      }

      // ---- E) drain h loads, then h-part MFMA (kk 2..5) ----
      asm volatile("s_waitcnt vmcnt(0)" ::: "memory");
      __builtin_amdgcn_sched_barrier(0);               // rule #18 fence
      MFMA4(hA0, hB0, 2);
      MFMA4(hA1, hB1, 3);
      MFMA4(hA2, hB2, 4);
      MFMA4(hA3, hB3, 5);
    } else {
      // t = 0: h is zero -> x contribution only
      const short8 xa0 = *reinterpret_cast<const short8*>(&Ash[l15][wk * 64 + l4 * 8]);
      const short8 xb0 = *reinterpret_cast<const short8*>(&Ash[16 + l15][wk * 64 + l4 * 8]);
      MFMA4(xa0, xb0, 0);
      const short8 xa1 = *reinterpret_cast<const short8*>(&Ash[l15][wk * 64 + 32 + l4 * 8]);
      const short8 xb1 = *reinterpret_cast<const short8*>(&Ash[16 + l15][wk * 64 + 32 + l4 * 8]);
      MFMA4(xa1, xb1, 1);
    }

    // ---- F) split-K partials to Gsh ----
    #pragma unroll
    for (int r = 0; r < 4; ++r) {                      // D: col=l15, row=l4*4+r
      Gsh[wk][0][l4 * 4 + r][l15] = g0a[r]; Gsh[wk][0][16 + l4 * 4 + r][l15] = g0b[r];
      Gsh[wk][1][l4 * 4 + r][l15] = g1a[r]; Gsh[wk][1][16 + l4 * 4 + r][l15] = g1b[r];
      Gsh[wk][2][l4 * 4 + r][l15] = g2a[r]; Gsh[wk][2][16 + l4 * 4 + r][l15] = g2b[r];
      Gsh[wk][3][l4 * 4 + r][l15] = g3a[r]; Gsh[wk][3][16 + l4 * 4 + r][l15] = g3b[r];
    }
    BAR_LDS();                                         // B2 (lgkm only)

    // ---- G) gates + cell update; publish h ASAP ----
    float h0v, h1v;
    {
      float gi0 = bi0, gi1 = bi1, gf0 = bf0, gf1 = bf1;
      float go0 = bo0, go1 = bo1, gc0 = bc0, gc1 = bc1;
      #pragma unroll
      for (int w = 0; w < 4; ++w) {
        const float2 a = *reinterpret_cast<const float2*>(&Gsh[w][0][grow_r][gcol0]);
        const float2 b = *reinterpret_cast<const float2*>(&Gsh[w][1][grow_r][gcol0]);
        const float2 c = *reinterpret_cast<const float2*>(&Gsh[w][2][grow_r][gcol0]);
        const float2 d = *reinterpret_cast<const float2*>(&Gsh[w][3][grow_r][gcol0]);
        gi0 += a.x; gi1 += a.y; gf0 += b.x; gf1 += b.y;
        go0 += c.x; go1 += c.y; gc0 += d.x; gc1 += d.y;
      }
      const float it0 = sigmoid_f(gi0), it1 = sigmoid_f(gi1);
      const float ft0 = sigmoid_f(gf0), ft1 = sigmoid_f(gf1);
      const float ot0 = sigmoid_f(go0), ot1 = sigmoid_f(go1);
      const float ct0 = tanh_f(gc0),    ct1 = tanh_f(gc1);
      cc0 = ft0 * cc0 + it0 * ct0;
      cc1 = ft1 * cc1 + it1 * ct1;
      h0v = ot0 * tanh_f(cc0);
      h1v = ot1 * tanh_f(cc1);
      unsigned hp;
      asm("v_cvt_pk_bf16_f32 %0, %1, %2" : "=v"(hp) : "v"(h0v), "v"(h1v));
      unsigned* hq = (t & 1) ? hbp1 : hbp0;            // parity t&1 buffer
      asm volatile("global_store_dword %0, %1, off sc0 sc1"
                   :: "v"(hq), "v"(hp) : "memory");    // bypass -> IF$
    }
    asm volatile("s_waitcnt vmcnt(0)" ::: "memory");   // h store acked at IF$
    BAR_LDS();                                         // B3: whole block done
    if (tid == 0) {                                    // publish "step t done"
      unsigned val = (unsigned)(t + 1);
      asm volatile("global_store_dword %0, %1, off sc0 sc1"
                   :: "v"(myflag), "v"(val) : "memory");
    }

    // ---- H) off-chain: out store + x(t+1)->Ash, overlaps propagation ----
    float2 hw; hw.x = h0v; hw.y = h1v;
    *reinterpret_cast<float2*>(outp + (size_t)t * H_) = hw;
    if (t + 1 < T_) {
      #pragma unroll
      for (int j = 0; j < 8; ++j) {
        unsigned lo, hi;
        asm("v_cvt_pk_bf16_f32 %0, %1, %2" : "=v"(lo) : "v"(xv[j].x), "v"(xv[j].y));
        asm("v_cvt_pk_bf16_f32 %0, %1, %2" : "=v"(hi) : "v"(xv[j].z), "v"(xv[j].w));
        uint2 p; p.x = lo; p.y = hi;
        *reinterpret_cast<uint2*>(&Ash[wave + 4 * j][lane * 4]) = p;
      }
    }
    BAR_LDS();                                         // loop-end: Ash ready
  }
}

extern "C" void kernel_launch(void* const* d_in, const int* in_sizes, int n_in,
                              void* d_out, int out_size, void* d_ws, size_t ws_size,
                              hipStream_t stream) {
  const float* x  = (const float*)d_in[0];
  const float* Wi = (const float*)d_in[1];
  const float* Ui = (const float*)d_in[2];
  const float* bi = (const float*)d_in[3];
  const float* Wf = (const float*)d_in[4];
  const float* Uf = (const float*)d_in[5];
  const float* bf = (const float*)d_in[6];
  const float* Wc = (const float*)d_in[7];
  const float* Uc = (const float*)d_in[8];
  const float* bc = (const float*)d_in[9];
  const float* Wo = (const float*)d_in[10];
  const float* Uo = (const float*)d_in[11];
  const float* bo = (const float*)d_in[12];
  float* out = (float*)d_out;

  unsigned short* BT = (unsigned short*)d_ws;                          // 3 MB
  unsigned short* hbuf = (unsigned short*)((char*)d_ws + 0x300000);    // 512 KB
  unsigned* flags = (unsigned*)((char*)d_ws + 0x380000);               // 16 KB

  prep_weights<<<(NG_ * K_ + 255) / 256, 256, 0, stream>>>(
      Wi, Wf, Wo, Wc, Ui, Uf, Uo, Uc, BT, flags);

  void* args[] = {(void*)&x, (void*)&BT, (void*)&bi, (void*)&bf, (void*)&bo,
                  (void*)&bc, (void*)&out, (void*)&flags, (void*)&hbuf};
  hipLaunchCooperativeKernel(reinterpret_cast<const void*>(&lstm_persist),
                             dim3(256), dim3(256), args, 0, stream);
}

// Round 14
// 1593.325 us; speedup vs baseline: 1.2468x; 1.2398x over previous
//
#include <hip/hip_runtime.h>
#include <hip/hip_bf16.h>
#include <cstdint>

// LSTM B=256 T=512 F=256 H=512 — persistent kernel, round 14.
// = round 5 VERBATIM (1483us, best PASS) + one zero-risk micro-opt:
// x->bf16 conversion via v_cvt_pk_bf16_f32 (r11-proven pattern) in x(0)
// staging and the off-chain phase G (fewer VALU ops between flag publish
// and next poll). Everything else — launch shape (256 blocks coop),
// ws layout (<=0x384000), sync fabric (sc0 sc1 IF$ bypass, parity hbuf,
// per-block monotone flags, per-thread fused poll+stage), phase order,
// LDS 58880B — byte-identical to round 5.
// Failure-envelope notes (13 rounds): keep 256-block coop launch, ws
// <=3.52MB, single self-contained asm load block, sc0 sc1 fabric.
// ws: BT 3MB @0 | hbuf[2] 512KB @0x300000 | flags 16KB @0x380000.

#define B_   256
#define T_   512
#define F_   256
#define H_   512
#define K_   768
#define NG_  2048
#define AW   776   // K_ + 8 bf16 pad

typedef __attribute__((ext_vector_type(8))) short short8;
typedef __attribute__((ext_vector_type(4))) float f32x4;

static __device__ __forceinline__ unsigned short f2bf(float f) {
  union { float f; unsigned u; } v; v.f = f;
  unsigned r = v.u + 0x7FFFu + ((v.u >> 16) & 1u);   // RNE
  return (unsigned short)(r >> 16);
}
static __device__ __forceinline__ float sigmoid_f(float x) {
  return __builtin_amdgcn_rcpf(1.f + __expf(-x));
}
static __device__ __forceinline__ float tanh_f(float x) {
  // tanh(x) = 1 - 2/(e^{2x}+1); inf/0 limits give +-1 correctly
  return 1.f - 2.f * __builtin_amdgcn_rcpf(__expf(2.f * x) + 1.f);
}

__global__ void prep_weights(const float* __restrict__ Wi, const float* __restrict__ Wf,
                             const float* __restrict__ Wo, const float* __restrict__ Wc,
                             const float* __restrict__ Ui, const float* __restrict__ Uf,
                             const float* __restrict__ Uo, const float* __restrict__ Uc,
                             unsigned short* __restrict__ BT,
                             unsigned* __restrict__ flags) {
  if (blockIdx.x == 0) {                      // re-zero flags every call
    unsigned* fp = flags + threadIdx.x * 16;
    unsigned z = 0;
    asm volatile("global_store_dword %0, %1, off sc0 sc1" :: "v"(fp), "v"(z) : "memory");
  }
  int idx = blockIdx.x * 256 + threadIdx.x;
  if (idx >= NG_ * K_) return;
  int col = idx / K_;
  int k   = idx - col * K_;
  int gate = col >> 9;       // 0:i 1:f 2:o 3:c (reference concat order)
  int hc   = col & 511;
  const float* Wg = (gate == 0) ? Wi : (gate == 1) ? Wf : (gate == 2) ? Wo : Wc;
  const float* Ug = (gate == 0) ? Ui : (gate == 1) ? Uf : (gate == 2) ? Uo : Uc;
  float v = (k < F_) ? Wg[k * H_ + hc] : Ug[(k - F_) * H_ + hc];
  BT[idx] = f2bf(v);
}

__global__ __launch_bounds__(256, 1)
void lstm_persist(const float* __restrict__ x,
                  const unsigned short* __restrict__ BT,
                  const float* __restrict__ bi, const float* __restrict__ bfp,
                  const float* __restrict__ bo, const float* __restrict__ bc,
                  float* __restrict__ out,
                  unsigned* __restrict__ flags,
                  unsigned short* __restrict__ hbuf) {
  __shared__ __align__(16) unsigned short Ash[32][AW];
  __shared__ float Gsh[4][32][18];             // +2 pad: conflict-free scatter

  const int tid = threadIdx.x;
  const int rg = blockIdx.x & 7;     // group (32 rows)
  const int cg = blockIdx.x >> 3;    // 16 h-cols strip (= flag slot)
  const int wave = tid >> 6, lane = tid & 63;
  const int l15 = lane & 15, l4 = lane >> 4;

  // ---- persistent B fragments: wave = gate, 16 cols, full K = 96 VGPRs ----
  short8 Breg[24];
  {
    const unsigned short* Bp =
        BT + (size_t)((wave << 9) | (cg << 4) | l15) * K_ + l4 * 8;
    #pragma unroll
    for (int kk = 0; kk < 24; ++kk)
      Breg[kk] = *reinterpret_cast<const short8*>(Bp + kk * 32);
  }

  // ---- gate-math thread mapping: 2 outputs (row, hc0..hc0+1) ----
  const int grow_r = tid >> 3;             // 0..31
  const int gcol0 = (tid & 7) * 2;         // 0..14 even
  const int hcg = (cg << 4) + gcol0;       // global h col
  const float bi0 = bi[hcg],  bi1 = bi[hcg + 1];
  const float bf0 = bfp[hcg], bf1 = bfp[hcg + 1];
  const float bo0 = bo[hcg],  bo1 = bo[hcg + 1];
  const float bc0 = bc[hcg],  bc1 = bc[hcg + 1];
  float cc0 = 0.f, cc1 = 0.f;              // cell state in registers
  const int grow = rg * 32 + grow_r;
  float* outp = out + (size_t)grow * T_ * H_ + hcg;
  unsigned* hbp0 = reinterpret_cast<unsigned*>(hbuf + (size_t)grow * H_ + hcg);
  unsigned* hbp1 = reinterpret_cast<unsigned*>(hbuf + (size_t)(B_ + grow) * H_ + hcg);

  // ---- stage x(0) ----
  #pragma unroll
  for (int j = 0; j < 8; ++j) {
    int f = tid + 256 * j; int row = f >> 6, k4 = f & 63;
    const float4 v = *reinterpret_cast<const float4*>(
        x + (size_t)(rg * 32 + row) * T_ * F_ + k4 * 4);
    unsigned lo, hi;
    asm("v_cvt_pk_bf16_f32 %0, %1, %2" : "=v"(lo) : "v"(v.x), "v"(v.y));
    asm("v_cvt_pk_bf16_f32 %0, %1, %2" : "=v"(hi) : "v"(v.z), "v"(v.w));
    uint2 p; p.x = lo; p.y = hi;
    *reinterpret_cast<uint2*>(&Ash[row][k4 * 4]) = p;
  }

  unsigned* myflag = flags + (rg * 32 + cg) * 16;
  // this thread's h chunk (cols lane*8..+8) comes entirely from peer lane>>1
  const unsigned* pollflag = flags + (rg * 32 + (lane >> 1)) * 16;
  const unsigned short* hsrc0 = hbuf;                    // parity 0
  const unsigned short* hsrc1 = hbuf + (size_t)B_ * H_;  // parity 1
  const unsigned vo = (unsigned)(((rg * 32 + wave) * H_ + lane * 8) * 2);

  for (int t = 0; t < T_; ++t) {
    // ---- A) per-thread poll source peer, then stage its h(t-1) chunk ----
    if (t > 0) {
      const unsigned want = (unsigned)t;
      unsigned cur;
      do {
        asm volatile("global_load_dword %0, %1, off sc0 sc1\n\ts_waitcnt vmcnt(0)"
                     : "=v"(cur) : "v"(pollflag) : "memory");
      } while (cur < want);
      const unsigned short* hsrc = ((t - 1) & 1) ? hsrc1 : hsrc0;
      short8 h0, h1, h2, h3, h4, h5, h6, h7;
      asm volatile(
        "global_load_dwordx4 %0, %8, %16 sc0 sc1\n\t"
        "global_load_dwordx4 %1, %9, %16 sc0 sc1\n\t"
        "global_load_dwordx4 %2, %10, %16 sc0 sc1\n\t"
        "global_load_dwordx4 %3, %11, %16 sc0 sc1\n\t"
        "global_load_dwordx4 %4, %12, %16 sc0 sc1\n\t"
        "global_load_dwordx4 %5, %13, %16 sc0 sc1\n\t"
        "global_load_dwordx4 %6, %14, %16 sc0 sc1\n\t"
        "global_load_dwordx4 %7, %15, %16 sc0 sc1\n\t"
        "s_waitcnt vmcnt(0)"
        : "=&v"(h0), "=&v"(h1), "=&v"(h2), "=&v"(h3),
          "=&v"(h4), "=&v"(h5), "=&v"(h6), "=&v"(h7)
        : "v"(vo), "v"(vo + 4096u), "v"(vo + 8192u), "v"(vo + 12288u),
          "v"(vo + 16384u), "v"(vo + 20480u), "v"(vo + 24576u), "v"(vo + 28672u),
          "s"(hsrc)
        : "memory");
      *reinterpret_cast<short8*>(&Ash[wave +  0][F_ + lane * 8]) = h0;
      *reinterpret_cast<short8*>(&Ash[wave +  4][F_ + lane * 8]) = h1;
      *reinterpret_cast<short8*>(&Ash[wave +  8][F_ + lane * 8]) = h2;
      *reinterpret_cast<short8*>(&Ash[wave + 12][F_ + lane * 8]) = h3;
      *reinterpret_cast<short8*>(&Ash[wave + 16][F_ + lane * 8]) = h4;
      *reinterpret_cast<short8*>(&Ash[wave + 20][F_ + lane * 8]) = h5;
      *reinterpret_cast<short8*>(&Ash[wave + 24][F_ + lane * 8]) = h6;
      *reinterpret_cast<short8*>(&Ash[wave + 28][F_ + lane * 8]) = h7;
    } else {
      #pragma unroll
      for (int j = 0; j < 8; ++j) {
        int f = tid + 256 * j; int row = f >> 6, c8 = f & 63;
        short8 z = {0, 0, 0, 0, 0, 0, 0, 0};
        *reinterpret_cast<short8*>(&Ash[row][F_ + c8 * 8]) = z;
      }
    }
    __syncthreads();                                   // B1

    // ---- B) issue x(t+1) prefetch (drains during MFMA phase) ----
    float4 xv[8];
    if (t + 1 < T_) {
      #pragma unroll
      for (int j = 0; j < 8; ++j) {
        int f = tid + 256 * j; int row = f >> 6, k4 = f & 63;
        xv[j] = *reinterpret_cast<const float4*>(
            x + ((size_t)(rg * 32 + row) * T_ + (t + 1)) * F_ + k4 * 4);
      }
    }

    // ---- C) MFMA: wave = gate, 32 rows x 16 cols x 768 K ----
    f32x4 acc0 = {0, 0, 0, 0}, acc1 = {0, 0, 0, 0};
    #pragma unroll
    for (int kk = 0; kk < 24; ++kk) {
      const int ks = kk * 32 + l4 * 8;
      const short8 a0 = *reinterpret_cast<const short8*>(&Ash[l15][ks]);
      const short8 a1 = *reinterpret_cast<const short8*>(&Ash[16 + l15][ks]);
      acc0 = __builtin_amdgcn_mfma_f32_16x16x32_bf16(a0, Breg[kk], acc0, 0, 0, 0);
      acc1 = __builtin_amdgcn_mfma_f32_16x16x32_bf16(a1, Breg[kk], acc1, 0, 0, 0);
    }
    #pragma unroll
    for (int r = 0; r < 4; ++r) {                      // D: col=l15, row=l4*4+r
      Gsh[wave][l4 * 4 + r][l15]      = acc0[r];
      Gsh[wave][16 + l4 * 4 + r][l15] = acc1[r];
    }
    __syncthreads();                                   // B2

    // ---- D) gates + cell update; publish h ASAP ----
    float h0, h1;
    {
      const float2 Gi = *reinterpret_cast<const float2*>(&Gsh[0][grow_r][gcol0]);
      const float2 Gf = *reinterpret_cast<const float2*>(&Gsh[1][grow_r][gcol0]);
      const float2 Go = *reinterpret_cast<const float2*>(&Gsh[2][grow_r][gcol0]);
      const float2 Gc = *reinterpret_cast<const float2*>(&Gsh[3][grow_r][gcol0]);
      const float it0 = sigmoid_f(Gi.x + bi0), it1 = sigmoid_f(Gi.y + bi1);
      const float ft0 = sigmoid_f(Gf.x + bf0), ft1 = sigmoid_f(Gf.y + bf1);
      const float ot0 = sigmoid_f(Go.x + bo0), ot1 = sigmoid_f(Go.y + bo1);
      const float ct0 = tanh_f(Gc.x + bc0),    ct1 = tanh_f(Gc.y + bc1);
      cc0 = ft0 * cc0 + it0 * ct0;
      cc1 = ft1 * cc1 + it1 * ct1;
      h0 = ot0 * tanh_f(cc0);
      h1 = ot1 * tanh_f(cc1);
      unsigned hp;
      asm("v_cvt_pk_bf16_f32 %0, %1, %2" : "=v"(hp) : "v"(h0), "v"(h1));
      unsigned* hq = (t & 1) ? hbp1 : hbp0;            // parity t&1 buffer
      asm volatile("global_store_dword %0, %1, off sc0 sc1"
                   :: "v"(hq), "v"(hp) : "memory");    // bypass -> IF$
    }
    asm volatile("s_waitcnt vmcnt(0)" ::: "memory");   // h store acked at IF$
    __syncthreads();                                   // B3: whole block done
    if (tid == 0) {                                    // publish "step t done"
      unsigned val = (unsigned)(t + 1);
      asm volatile("global_store_dword %0, %1, off sc0 sc1"
                   :: "v"(myflag), "v"(val) : "memory");
    }

    // ---- E) off-chain work: overlaps peer flag propagation ----
    float2 hw; hw.x = h0; hw.y = h1;
    *reinterpret_cast<float2*>(outp + (size_t)t * H_) = hw;
    if (t + 1 < T_) {
      #pragma unroll
      for (int j = 0; j < 8; ++j) {
        int f = tid + 256 * j; int row = f >> 6, k4 = f & 63;
        unsigned lo, hi;
        asm("v_cvt_pk_bf16_f32 %0, %1, %2" : "=v"(lo) : "v"(xv[j].x), "v"(xv[j].y));
        asm("v_cvt_pk_bf16_f32 %0, %1, %2" : "=v"(hi) : "v"(xv[j].z), "v"(xv[j].w));
        uint2 p; p.x = lo; p.y = hi;
        *reinterpret_cast<uint2*>(&Ash[row][k4 * 4]) = p;
      }
    }
  }
}

extern "C" void kernel_launch(void* const* d_in, const int* in_sizes, int n_in,
                              void* d_out, int out_size, void* d_ws, size_t ws_size,
                              hipStream_t stream) {
  const float* x  = (const float*)d_in[0];
  const float* Wi = (const float*)d_in[1];
  const float* Ui = (const float*)d_in[2];
  const float* bi = (const float*)d_in[3];
  const float* Wf = (const float*)d_in[4];
  const float* Uf = (const float*)d_in[5];
  const float* bf = (const float*)d_in[6];
  const float* Wc = (const float*)d_in[7];
  const float* Uc = (const float*)d_in[8];
  const float* bc = (const float*)d_in[9];
  const float* Wo = (const float*)d_in[10];
  const float* Uo = (const float*)d_in[11];
  const float* bo = (const float*)d_in[12];
  float* out = (float*)d_out;

  unsigned short* BT = (unsigned short*)d_ws;                          // 3 MB
  unsigned short* hbuf = (unsigned short*)((char*)d_ws + 0x300000);    // 512 KB
  unsigned* flags = (unsigned*)((char*)d_ws + 0x380000);               // 16 KB

  prep_weights<<<(NG_ * K_ + 255) / 256, 256, 0, stream>>>(
      Wi, Wf, Wo, Wc, Ui, Uf, Uo, Uc, BT, flags);

  void* args[] = {(void*)&x, (void*)&BT, (void*)&bi, (void*)&bf, (void*)&bo,
                  (void*)&bc, (void*)&out, (void*)&flags, (void*)&hbuf};
  hipLaunchCooperativeKernel(reinterpret_cast<const void*>(&lstm_persist),
                             dim3(256), dim3(256), args, 0, stream);
}